// Round 7
// baseline (3225.509 us; speedup 1.0000x reference)
//
#include <hip/hip_runtime.h>
#include <math.h>

#define CIN   3
#define DIN   16
#define HWIN  64
#define COUT  24
#define DOUT  14
#define HOUT  62
#define WOUT  62

#define TILE_H   4
#define NTILES   16                     // 62 rows -> 16 tiles of 4 (last 2 masked)
#define NTHR     768                    // 12 waves = (row 0..3) x (co-octet 0..2)
#define ROWS_IN  6                      // input rows per tile
#define RPW      64                     // row words: NO pad (row is wave-uniform)
#define PLANE_W  (CIN * ROWS_IN * RPW)  // 1152 words per depth plane
#define XSLAB_W  (DIN * PLANE_W)        // 18432 words = 73728 B
#define LDS_W    (XSLAB_W + 4)          // +4: b64 tail overread safety
#define WCO      28                     // padded weights per (cin,co) in ws

// x: [128][3][16][64][64]  w: [24][3][3][3][3]  out: softmax_co(min_dz(conv+bias))
//
// v9 vs v8 (spills at VGPR=84: 338MB scratch writes; 4-row x-read pattern
// inherently bank-conflicted ~21cy/read):
//  - wave owns ONE output row + one co-octet: x-read addr = 8*wg words ->
//    32 distinct words + 8-way same-address broadcast = v2's measured
//    conflict-free pattern. RP=64 (row stride irrelevant intra-wave).
//  - weights per-lane in VGPRs, 27 at a time (one (cin,co) slice), reloaded
//    per (chunk,cin) from repacked ws: 42 VMEM loads/wave total, amortized
//    over 1512 FMA each batch.
//  - dz chunks 7+7, plane-sweep: 3-instr x-row read feeds up to 72 FMA;
//    acc[7][8]=56 regs; total live ~115 < 128 -> no spills.
//  - 12 waves/CU (3/SIMD), slab staged once via global_load_lds, ONE barrier.

__device__ __forceinline__ void gload_lds_dw(const float* g, float* l) {
    __builtin_amdgcn_global_load_lds(
        (const __attribute__((address_space(1))) unsigned int*)g,
        (__attribute__((address_space(3))) unsigned int*)l, 4, 0, 0);
}

__global__ void repack_w_v9(const float* __restrict__ w, float* __restrict__ ws) {
    const int i = threadIdx.x + blockIdx.x * blockDim.x;
    if (i < COUT * 81) {
        const int co  = i / 81;
        const int rem = i % 81;          // = cin*27 + (kd*9 + kh*3 + kw)
        const int cin = rem / 27;
        const int tap = rem % 27;
        ws[(cin * COUT + co) * WCO + tap] = w[i];
    }
}

__global__ __launch_bounds__(NTHR, 3) void conv_min_softmax_v9(
    const float* __restrict__ x,
    const float* __restrict__ ws,
    const float* __restrict__ bias,
    float* __restrict__ out)
{
    __shared__ __align__(16) float smem[LDS_W];

    const int tid  = threadIdx.x;
    const int bid  = blockIdx.x;
    const int rt   = bid & (NTILES - 1);
    const int b    = bid >> 4;

    const int q    = __builtin_amdgcn_readfirstlane(tid >> 6);  // wave 0..11
    const int lane = tid & 63;
    const int row  = q & 3;              // output row within tile (wave-uniform)
    const int oct  = q >> 2;             // co octet 0..2 (wave-uniform)
    const int cop  = lane >> 3;          // 0..7
    const int wg   = lane & 7;           // 0..7 -> cols 8wg .. 8wg+7
    const int co   = oct * 8 + cop;      // this lane's output channel

    // ---- stage all 16 planes via global_load_lds: 288 rows, 24 per wave ----
    {
        const float* __restrict__ xb =
            x + (size_t)b * (CIN * DIN * HWIN * HWIN) + lane;
        #pragma unroll 1
        for (int k = 0; k < 24; ++k) {
            const int j    = q * 24 + k;         // 0..287
            const int p    = j / 18;             // plane
            const int sub  = j % 18;
            const int ci   = sub / 6;
            const int rr   = sub % 6;
            const int grow = min(rt * TILE_H + rr, HWIN - 1);    // clamp last tile
            gload_lds_dw(xb + ((size_t)(ci * DIN + p) * (HWIN * HWIN) + grow * HWIN),
                         &smem[p * PLANE_W + (ci * ROWS_IN + rr) * RPW]);
        }
    }
    const float bco = bias[co];
    __syncthreads();             // drains global_load_lds; the ONLY main barrier

    float m[8];
    #pragma unroll
    for (int i = 0; i < 8; ++i) m[i] = 1e30f;

    #pragma unroll 1
    for (int ch = 0; ch < 2; ++ch) {             // dz = 7*ch .. 7*ch+6
        const int p0 = ch * 7;

        float acc[7][8];
        #pragma unroll
        for (int d = 0; d < 7; ++d)
            #pragma unroll
            for (int i = 0; i < 8; ++i) acc[d][i] = 0.f;

        #pragma unroll 1
        for (int cin = 0; cin < CIN; ++cin) {
            // this lane's 27 weights for (cin, co): 7 coalesced float4 loads
            float wv[28];
            {
                const float4* __restrict__ wp =
                    (const float4*)(ws + (cin * COUT + co) * WCO);
                #pragma unroll
                for (int t = 0; t < 7; ++t) *(float4*)&wv[t * 4] = wp[t];
            }

            #pragma unroll
            for (int pp = 0; pp < 9; ++pp) {     // plane sweep: row read ONCE
                #pragma unroll
                for (int kh = 0; kh < 3; ++kh) {
                    const float* rp = &smem[(p0 + pp) * PLANE_W +
                                            (cin * ROWS_IN + row + kh) * RPW + wg * 8];
                    const float4 a4 = *(const float4*)rp;        // b128: conflict-free
                    const float4 b4 = *(const float4*)(rp + 4);  // b128
                    const float2 c2 = *(const float2*)(rp + 8);  // b64
                    const float xr[10] = { a4.x, a4.y, a4.z, a4.w,
                                           b4.x, b4.y, b4.z, b4.w, c2.x, c2.y };
                    #pragma unroll
                    for (int kd = 0; kd < 3; ++kd) {
                        const int d = pp - kd;
                        if (d < 0 || d >= 7) continue;           // compile-time pruned
                        #pragma unroll
                        for (int kw = 0; kw < 3; ++kw) {
                            const float wt = wv[kd * 9 + kh * 3 + kw];
                            #pragma unroll
                            for (int i = 0; i < 8; ++i)
                                acc[d][i] = fmaf(wt, xr[i + kw], acc[d][i]);
                        }
                    }
                }
            }
        }

        #pragma unroll
        for (int d = 0; d < 7; ++d)
            #pragma unroll
            for (int i = 0; i < 8; ++i)
                m[i] = fminf(m[i], acc[d][i]);
    }

    __syncthreads();     // all slab reads done; overlay sm[24][4][64] on smem

    {
        const int p = co * 256 + row * 64 + wg * 8;
        float4 lo = { m[0] + bco, m[1] + bco, m[2] + bco, m[3] + bco };
        float4 hi = { m[4] + bco, m[5] + bco, m[6] + bco, m[7] + bco };
        *(float4*)&smem[p]     = lo;
        *(float4*)&smem[p + 4] = hi;
    }
    __syncthreads();

    if (tid < 256) {                      // 4 rows x 64 cols, one pixel per thread
        const int rw  = tid >> 6;
        const int col = tid & 63;
        const int ho  = rt * TILE_H + rw;
        if (col < WOUT && ho < HOUT) {
            float v[COUT];
            float mx = -1e30f;
            #pragma unroll
            for (int c = 0; c < COUT; ++c) {
                v[c] = smem[c * 256 + rw * 64 + col];
                mx = fmaxf(mx, v[c]);
            }
            float s = 0.f;
            #pragma unroll
            for (int c = 0; c < COUT; ++c) { v[c] = __expf(v[c] - mx); s += v[c]; }
            const float inv = 1.f / s;
            float* ob = out + (size_t)b * COUT * (HOUT * WOUT) + ho * WOUT + col;
            #pragma unroll
            for (int c = 0; c < COUT; ++c)
                ob[(size_t)c * (HOUT * WOUT)] = v[c] * inv;
        }
    }
}

extern "C" void kernel_launch(void* const* d_in, const int* in_sizes, int n_in,
                              void* d_out, int out_size, void* d_ws, size_t ws_size,
                              hipStream_t stream) {
    const float* x    = (const float*)d_in[0];
    const float* w    = (const float*)d_in[1];
    const float* bias = (const float*)d_in[2];
    float* out = (float*)d_out;
    float* ws  = (float*)d_ws;

    repack_w_v9<<<8, 256, 0, stream>>>(w, ws);
    conv_min_softmax_v9<<<128 * NTILES, NTHR, 0, stream>>>(x, ws, bias, out);
}

// Round 8
// 3212.403 us; speedup vs baseline: 1.0041x; 1.0041x over previous
//
#include <hip/hip_runtime.h>
#include <math.h>

#define CIN   3
#define DIN   16
#define HWIN  64
#define COUT  24
#define DOUT  14
#define HOUT  62
#define WOUT  62

#define TILE_H   4
#define NTILES   16                     // 62 rows -> 16 tiles of 4 (last 2 masked)
#define NTHR     768                    // 12 waves = (row 0..3) x (co-octet 0..2)
#define ROWS_IN  6                      // input rows per tile
#define RPW      64                     // row words: NO pad (row is wave-uniform)
#define PLANE_W  (CIN * ROWS_IN * RPW)  // 1152 words per depth plane
#define XSLAB_W  (DIN * PLANE_W)        // 18432 words = 73728 B
#define LDS_W    (XSLAB_W + 4)          // +4: b64 tail overread safety
#define WCO      28                     // padded weights per (cin,co) in ws

// x: [128][3][16][64][64]  w: [24][3][3][3][3]  out: softmax_co(min_dz(conv+bias))
//
// v10 = v9 + amdgpu_waves_per_eu(2,3). v9's 3225us was PURE scratch spill:
// 15GB HBM traffic/dispatch, VGPR=84 vs ~120 live. Root cause: 74KB LDS lets
// 2 blocks/CU fit -> occupancy heuristic targeted 6 waves/EU -> 512/6=84 regs.
// waves_per_eu(2,3) pins the target at <=3 waves/EU (budget 170-256), so the
// ~120 live values (acc[7][8]=56 + wv[28] + xr[10] + m[8] + addr) fit with
// zero spills. Structure unchanged: plane-sweep dz-chunks of 7, x-row read
// once feeds up to 72 FMAs (DS/FMA cycle ratio ~0.29 vs 0.25 budget ->
// mildly DS-bound, ~207us floor + FMA 181us).

__device__ __forceinline__ void gload_lds_dw(const float* g, float* l) {
    __builtin_amdgcn_global_load_lds(
        (const __attribute__((address_space(1))) unsigned int*)g,
        (__attribute__((address_space(3))) unsigned int*)l, 4, 0, 0);
}

__global__ void repack_w_v10(const float* __restrict__ w, float* __restrict__ ws) {
    const int i = threadIdx.x + blockIdx.x * blockDim.x;
    if (i < COUT * 81) {
        const int co  = i / 81;
        const int rem = i % 81;          // = cin*27 + (kd*9 + kh*3 + kw)
        const int cin = rem / 27;
        const int tap = rem % 27;
        ws[(cin * COUT + co) * WCO + tap] = w[i];
    }
}

__global__
__attribute__((amdgpu_flat_work_group_size(NTHR, NTHR)))
__attribute__((amdgpu_waves_per_eu(2, 3)))
void conv_min_softmax_v10(
    const float* __restrict__ x,
    const float* __restrict__ ws,
    const float* __restrict__ bias,
    float* __restrict__ out)
{
    __shared__ __align__(16) float smem[LDS_W];

    const int tid  = threadIdx.x;
    const int bid  = blockIdx.x;
    const int rt   = bid & (NTILES - 1);
    const int b    = bid >> 4;

    const int q    = __builtin_amdgcn_readfirstlane(tid >> 6);  // wave 0..11
    const int lane = tid & 63;
    const int row  = q & 3;              // output row within tile (wave-uniform)
    const int oct  = q >> 2;             // co octet 0..2 (wave-uniform)
    const int cop  = lane >> 3;          // 0..7
    const int wg   = lane & 7;           // 0..7 -> cols 8wg .. 8wg+7
    const int co   = oct * 8 + cop;      // this lane's output channel

    // ---- stage all 16 planes via global_load_lds: 288 rows, 24 per wave ----
    {
        const float* __restrict__ xb =
            x + (size_t)b * (CIN * DIN * HWIN * HWIN) + lane;
        #pragma unroll 1
        for (int k = 0; k < 24; ++k) {
            const int j    = q * 24 + k;         // 0..287
            const int p    = j / 18;             // plane
            const int sub  = j % 18;
            const int ci   = sub / 6;
            const int rr   = sub % 6;
            const int grow = min(rt * TILE_H + rr, HWIN - 1);    // clamp last tile
            gload_lds_dw(xb + ((size_t)(ci * DIN + p) * (HWIN * HWIN) + grow * HWIN),
                         &smem[p * PLANE_W + (ci * ROWS_IN + rr) * RPW]);
        }
    }
    const float bco = bias[co];
    __syncthreads();             // drains global_load_lds; the ONLY main barrier

    float m[8];
    #pragma unroll
    for (int i = 0; i < 8; ++i) m[i] = 1e30f;

    #pragma unroll 1
    for (int ch = 0; ch < 2; ++ch) {             // dz = 7*ch .. 7*ch+6
        const int p0 = ch * 7;

        float acc[7][8];
        #pragma unroll
        for (int d = 0; d < 7; ++d)
            #pragma unroll
            for (int i = 0; i < 8; ++i) acc[d][i] = 0.f;

        #pragma unroll 1
        for (int cin = 0; cin < CIN; ++cin) {
            // this lane's 27 weights for (cin, co): 7 coalesced float4 loads
            float wv[28];
            {
                const float4* __restrict__ wp =
                    (const float4*)(ws + (cin * COUT + co) * WCO);
                #pragma unroll
                for (int t = 0; t < 7; ++t) *(float4*)&wv[t * 4] = wp[t];
            }

            #pragma unroll
            for (int pp = 0; pp < 9; ++pp) {     // plane sweep: row read ONCE
                #pragma unroll
                for (int kh = 0; kh < 3; ++kh) {
                    const float* rp = &smem[(p0 + pp) * PLANE_W +
                                            (cin * ROWS_IN + row + kh) * RPW + wg * 8];
                    const float4 a4 = *(const float4*)rp;        // b128 (2-way alias: free)
                    const float4 b4 = *(const float4*)(rp + 4);  // b128
                    const float2 c2 = *(const float2*)(rp + 8);  // b64
                    const float xr[10] = { a4.x, a4.y, a4.z, a4.w,
                                           b4.x, b4.y, b4.z, b4.w, c2.x, c2.y };
                    #pragma unroll
                    for (int kd = 0; kd < 3; ++kd) {
                        const int d = pp - kd;
                        if (d < 0 || d >= 7) continue;           // compile-time pruned
                        #pragma unroll
                        for (int kw = 0; kw < 3; ++kw) {
                            const float wt = wv[kd * 9 + kh * 3 + kw];
                            #pragma unroll
                            for (int i = 0; i < 8; ++i)
                                acc[d][i] = fmaf(wt, xr[i + kw], acc[d][i]);
                        }
                    }
                }
            }
        }

        #pragma unroll
        for (int d = 0; d < 7; ++d)
            #pragma unroll
            for (int i = 0; i < 8; ++i)
                m[i] = fminf(m[i], acc[d][i]);
    }

    __syncthreads();     // all slab reads done; overlay sm[24][4][64] on smem

    {
        const int p = co * 256 + row * 64 + wg * 8;
        float4 lo = { m[0] + bco, m[1] + bco, m[2] + bco, m[3] + bco };
        float4 hi = { m[4] + bco, m[5] + bco, m[6] + bco, m[7] + bco };
        *(float4*)&smem[p]     = lo;
        *(float4*)&smem[p + 4] = hi;
    }
    __syncthreads();

    if (tid < 256) {                      // 4 rows x 64 cols, one pixel per thread
        const int rw  = tid >> 6;
        const int col = tid & 63;
        const int ho  = rt * TILE_H + rw;
        if (col < WOUT && ho < HOUT) {
            float v[COUT];
            float mx = -1e30f;
            #pragma unroll
            for (int c = 0; c < COUT; ++c) {
                v[c] = smem[c * 256 + rw * 64 + col];
                mx = fmaxf(mx, v[c]);
            }
            float s = 0.f;
            #pragma unroll
            for (int c = 0; c < COUT; ++c) { v[c] = __expf(v[c] - mx); s += v[c]; }
            const float inv = 1.f / s;
            float* ob = out + (size_t)b * COUT * (HOUT * WOUT) + ho * WOUT + col;
            #pragma unroll
            for (int c = 0; c < COUT; ++c)
                ob[(size_t)c * (HOUT * WOUT)] = v[c] * inv;
        }
    }
}

extern "C" void kernel_launch(void* const* d_in, const int* in_sizes, int n_in,
                              void* d_out, int out_size, void* d_ws, size_t ws_size,
                              hipStream_t stream) {
    const float* x    = (const float*)d_in[0];
    const float* w    = (const float*)d_in[1];
    const float* bias = (const float*)d_in[2];
    float* out = (float*)d_out;
    float* ws  = (float*)d_ws;

    repack_w_v10<<<8, 256, 0, stream>>>(w, ws);
    conv_min_softmax_v10<<<128 * NTILES, NTHR, 0, stream>>>(x, ws, bias, out);
}